// Round 7
// baseline (86.752 us; speedup 1.0000x reference)
//
#include <hip/hip_runtime.h>
#include <math.h>

#define NCOL 8192
#define NROW 4096
#define KSEL 819
#define NW   4             // independent waves (rows) per block — NO block barriers
#define TPB  (NW * 64)
#define LPT  32            // f32x4 per lane = 128 elements per lane
#define NBKT 1024
#define KPIV 0xBF866666u   // f2k(1.05f): survivor pivot in key space
#define LCAP 64

typedef float f32x4 __attribute__((ext_vector_type(4)));

// Per-column boost factors, recomputed every launch (deterministic).
__device__ __align__(16) float g_boost[NCOL];

__global__ void boost_kernel(const float* __restrict__ duty) {
    int i = blockIdx.x * blockDim.x + threadIdx.x;
    if (i < NCOL) {
        // target_density = 819/8192 exactly; boost_strength = 1
        float diff = (0.0999755859375f - duty[i]);
        g_boost[i] = (float)exp((double)diff);   // correctly-rounded f32 exp (matches np)
    }
}

__device__ __forceinline__ unsigned f2k(float f) {
    // monotone float -> uint map (total order)
    unsigned u = __float_as_uint(f);
    return u ^ (0x80000000u | (unsigned)((int)u >> 31));
}
__device__ __forceinline__ int kbucket(unsigned k) {
    // pure-integer monotone bucket; survivors (k>KPIV) -> [0, 1023]
    int b = (int)(k >> 14) - (int)(KPIV >> 14);
    return (b > NBKT - 1) ? (NBKT - 1) : b;
}

// intra-wave LDS sync: DS ops from one wave complete in order; we only need the
// counter drained + compiler ordering (memory clobber). No __syncthreads.
#define WSYNC() asm volatile("s_waitcnt lgkmcnt(0)" ::: "memory")
#define VSYNC() asm volatile("s_waitcnt vmcnt(0)" ::: "memory")

__global__ __launch_bounds__(TPB) void kwinners_kernel(const float* __restrict__ x,
                                                       float* __restrict__ out) {
    __shared__ __align__(16) int lds_hist[NW][NBKT];      // 16 KB (per-wave 4 KB)
    __shared__ __align__(16) unsigned lds_list[NW][LCAP]; // 1 KB
    __shared__ int lds_s[NW][4];                          // cnt, sel, R1, E

    const int lane = threadIdx.x & 63;
    const int w = threadIdx.x >> 6;
    const int row = blockIdx.x * NW + w;

    int* hist = lds_hist[w];
    unsigned* list = lds_list[w];
    int* sc = lds_s[w];
    int4* h4 = (int4*)hist;

    const f32x4* x4 = (const f32x4*)(x + (size_t)row * NCOL);
    const f32x4* b4 = (const f32x4*)g_boost;
    f32x4* o4 = (f32x4*)(out + (size_t)row * NCOL);

    // zero hist + counter (same-wave DS ops are in order: zeros precede atomics)
    {
        const int4 z = make_int4(0, 0, 0, 0);
        h4[4 * lane + 0] = z; h4[4 * lane + 1] = z;
        h4[4 * lane + 2] = z; h4[4 * lane + 3] = z;
        if (lane == 0) sc[0] = 0;
    }

    // ---- pass A: survivor histogram in key space ----
#pragma unroll 8
    for (int j = 0; j < LPT; ++j) {
        f32x4 xx = x4[lane + 64 * j];
        f32x4 bb = b4[lane + 64 * j];
        unsigned k0 = f2k(xx.x * bb.x), k1 = f2k(xx.y * bb.y);
        unsigned k2 = f2k(xx.z * bb.z), k3 = f2k(xx.w * bb.w);
        if (k0 > KPIV) atomicAdd(&hist[kbucket(k0)], 1);
        if (k1 > KPIV) atomicAdd(&hist[kbucket(k1)], 1);
        if (k2 > KPIV) atomicAdd(&hist[kbucket(k2)], 1);
        if (k3 > KPIV) atomicAdd(&hist[kbucket(k3)], 1);
    }
    WSYNC();

    // ---- scan 1024 buckets (16/lane), wave suffix sums ----
    int arr[16];
    {
        int4 a0 = h4[4 * lane + 0], a1 = h4[4 * lane + 1];
        int4 a2 = h4[4 * lane + 2], a3 = h4[4 * lane + 3];
        arr[0] = a0.x; arr[1] = a0.y; arr[2] = a0.z; arr[3] = a0.w;
        arr[4] = a1.x; arr[5] = a1.y; arr[6] = a1.z; arr[7] = a1.w;
        arr[8] = a2.x; arr[9] = a2.y; arr[10] = a2.z; arr[11] = a2.w;
        arr[12] = a3.x; arr[13] = a3.y; arr[14] = a3.z; arr[15] = a3.w;
    }
    int ts = 0;
#pragma unroll
    for (int b = 0; b < 16; ++b) ts += arr[b];
    int s = ts;
#pragma unroll
    for (int off = 1; off < 64; off <<= 1) {
        int o = __shfl_down(s, off);
        if (lane + off < 64) s += o;
    }
    const int C = __shfl(s, 0);        // total survivors (wave-uniform)

    unsigned th = 0; int Rf = 0, E = 0;
    bool fb = (C < KSEL);

    if (!fb) {
        const int S_ab = s - ts;       // keys in buckets above my range
        if (S_ab < KSEL && S_ab + ts >= KSEL) {   // exactly one lane
            int cum = S_ab;
#pragma unroll
            for (int b = 15; b >= 0; --b) {
                int nx = cum + arr[b];
                if (cum < KSEL && nx >= KSEL) { sc[1] = 16 * lane + b; sc[2] = KSEL - cum; }
                cum = nx;
            }
        }
        WSYNC();
        const int sel = sc[1];
        const int R1 = sc[2];

        // ---- pass B: gather selected bucket's keys ----
#pragma unroll 8
        for (int j = 0; j < LPT; ++j) {
            f32x4 xx = x4[lane + 64 * j];
            f32x4 bb = b4[lane + 64 * j];
            unsigned kk[4] = {f2k(xx.x * bb.x), f2k(xx.y * bb.y),
                              f2k(xx.z * bb.z), f2k(xx.w * bb.w)};
#pragma unroll
            for (int c = 0; c < 4; ++c)
                if (kk[c] > KPIV && kbucket(kk[c]) == sel) {
                    int sl = atomicAdd(&sc[0], 1);
                    if (sl < LCAP) list[sl] = kk[c];
                }
        }
        WSYNC();
        const int n = sc[0];
        if (n > LCAP) fb = true;
        else {
            // propose th: exact R1-th largest of the tiny list (all-shuffle)
            unsigned myk = (lane < n) ? list[lane] : 0u;
            int g = 0, e = 0;
            for (int i = 0; i < n; ++i) {
                unsigned ki = __shfl(myk, i);
                g += (ki > myk) ? 1 : 0;
                e += (ki == myk) ? 1 : 0;
            }
            unsigned cand = (lane < n && g < R1 && g + e >= R1) ? myk : 0u;
#pragma unroll
            for (int off = 1; off < 64; off <<= 1) {
                unsigned o = __shfl_xor(cand, off);
                cand = (o > cand) ? o : cand;
            }
            th = cand;

            // ---- pass C: certify + speculative write (fused) ----
            int GE = 0;
#pragma unroll 8
            for (int j = 0; j < LPT; ++j) {
                f32x4 xx = x4[lane + 64 * j];
                f32x4 bb = b4[lane + 64 * j];
                unsigned k0 = f2k(xx.x * bb.x), k1 = f2k(xx.y * bb.y);
                unsigned k2 = f2k(xx.z * bb.z), k3 = f2k(xx.w * bb.w);
                GE += (k0 > th) + (k1 > th) + (k2 > th) + (k3 > th);
                GE += ((k0 == th) + (k1 == th) + (k2 == th) + (k3 == th)) << 16;
                f32x4 r;
                r.x = (k0 >= th) ? xx.x : 0.0f;
                r.y = (k1 >= th) ? xx.y : 0.0f;
                r.z = (k2 >= th) ? xx.z : 0.0f;
                r.w = (k3 >= th) ? xx.w : 0.0f;
                __builtin_nontemporal_store(r, &o4[lane + 64 * j]);
            }
#pragma unroll
            for (int off = 1; off < 64; off <<= 1) GE += __shfl_xor(GE, off);
            const int G = GE & 0xFFFF, Eg = GE >> 16;
            if (G < KSEL && G + Eg >= KSEL) { Rf = KSEL - G; E = Eg; }
            else fb = true;            // certification failed -> guaranteed path
        }
    }

    if (fb) {
        // per-wave 4x8-bit key radix select (guaranteed), then rewrite the row
        VSYNC();
        unsigned prefix = 0; int R = KSEL;
        for (int p = 0; p < 4; ++p) {
            const int sh = 24 - 8 * p;
            ((int4*)hist)[lane] = make_int4(0, 0, 0, 0);   // 256 bins, in-order vs atomics
            for (int j = 0; j < LPT; ++j) {
                f32x4 xx = x4[lane + 64 * j];
                f32x4 bb = b4[lane + 64 * j];
                unsigned kk[4] = {f2k(xx.x * bb.x), f2k(xx.y * bb.y),
                                  f2k(xx.z * bb.z), f2k(xx.w * bb.w)};
#pragma unroll
                for (int c = 0; c < 4; ++c)
                    if (p == 0 || (kk[c] >> (sh + 8)) == (prefix >> (sh + 8)))
                        atomicAdd(&hist[(kk[c] >> sh) & 255u], 1);
            }
            WSYNC();
            int4 hh = ((int4*)hist)[lane];
            int a4[4] = {hh.x, hh.y, hh.z, hh.w};
            int t4 = a4[0] + a4[1] + a4[2] + a4[3];
            int s2 = t4;
#pragma unroll
            for (int off = 1; off < 64; off <<= 1) {
                int o = __shfl_down(s2, off);
                if (lane + off < 64) s2 += o;
            }
            const int S_ab2 = s2 - t4;
            if (S_ab2 < R && S_ab2 + t4 >= R) {
                int cum = S_ab2;
#pragma unroll
                for (int b = 3; b >= 0; --b) {
                    int nx = cum + a4[b];
                    if (cum < R && nx >= R) { sc[1] = 4 * lane + b; sc[2] = R - cum; sc[3] = a4[b]; }
                    cum = nx;
                }
            }
            WSYNC();
            prefix |= ((unsigned)sc[1]) << sh;
            R = sc[2];
        }
        th = prefix; Rf = R; E = sc[3];
        for (int j = 0; j < LPT; ++j) {
            f32x4 xx = x4[lane + 64 * j];
            f32x4 bb = b4[lane + 64 * j];
            unsigned k0 = f2k(xx.x * bb.x), k1 = f2k(xx.y * bb.y);
            unsigned k2 = f2k(xx.z * bb.z), k3 = f2k(xx.w * bb.w);
            f32x4 r;
            r.x = (k0 >= th) ? xx.x : 0.0f;
            r.y = (k1 >= th) ? xx.y : 0.0f;
            r.z = (k2 >= th) ? xx.z : 0.0f;
            r.w = (k3 >= th) ? xx.w : 0.0f;
            o4[lane + 64 * j] = r;
        }
    }

    // ---- tie demotion (lax.top_k keeps lowest columns) — rare ----
    if (E > Rf) {
        VSYNC();                                   // drain row writes first
        unsigned short* tl = (unsigned short*)hist; // cap 2048 cols
        if (lane == 0) sc[0] = 0;
        for (int j = 0; j < LPT; ++j) {
            f32x4 xx = x4[lane + 64 * j];
            f32x4 bb = b4[lane + 64 * j];
            unsigned kk[4] = {f2k(xx.x * bb.x), f2k(xx.y * bb.y),
                              f2k(xx.z * bb.z), f2k(xx.w * bb.w)};
#pragma unroll
            for (int c = 0; c < 4; ++c)
                if (kk[c] == th) {
                    int sl = atomicAdd(&sc[0], 1);
                    if (sl < 2048) tl[sl] = (unsigned short)(4 * (lane + 64 * j) + c);
                }
        }
        WSYNC();
        const int nt = sc[0];
        float* orow = out + (size_t)row * NCOL;
        if (nt <= 2048) {
            for (int j = 0; j < LPT; ++j) {
                f32x4 xx = x4[lane + 64 * j];
                f32x4 bb = b4[lane + 64 * j];
                unsigned kk[4] = {f2k(xx.x * bb.x), f2k(xx.y * bb.y),
                                  f2k(xx.z * bb.z), f2k(xx.w * bb.w)};
#pragma unroll
                for (int c = 0; c < 4; ++c)
                    if (kk[c] == th) {
                        const int col = 4 * (lane + 64 * j) + c;
                        int rk = 0;
                        for (int i = 0; i < nt; ++i) rk += (tl[i] < col) ? 1 : 0;
                        if (rk >= Rf) orow[col] = 0.0f;
                    }
            }
        } else if (lane == 0) {      // >2048 identical keys: never, but correct
            int seen = 0;
            for (int col = 0; col < NCOL; ++col) {
                float v = x[(size_t)row * NCOL + col] * g_boost[col];
                if (f2k(v) == th) { if (seen >= Rf) orow[col] = 0.0f; ++seen; }
            }
        }
    }
}

extern "C" void kernel_launch(void* const* d_in, const int* in_sizes, int n_in,
                              void* d_out, int out_size, void* d_ws, size_t ws_size,
                              hipStream_t stream) {
    const float* x = (const float*)d_in[0];        // [4096, 8192] f32
    const float* duty = (const float*)d_in[1];     // [8192] f32
    float* out = (float*)d_out;                    // [4096, 8192] f32
    (void)in_sizes; (void)n_in; (void)out_size; (void)d_ws; (void)ws_size;

    boost_kernel<<<(NCOL + 255) / 256, 256, 0, stream>>>(duty);
    kwinners_kernel<<<NROW / NW, TPB, 0, stream>>>(x, out);
}